// Round 3
// baseline (188.635 us; speedup 1.0000x reference)
//
#include <hip/hip_runtime.h>

// Problem constants (SubOut_60206851555968): B=8, U=E=1024, D=P=256, fp32 in/out.
#define BDIM 8
#define UDIM 1024
#define EDIM 1024
#define DDIM 256
#define PDIM 256

typedef __attribute__((ext_vector_type(8))) short bf16x8;   // 8 bf16 = 4 VGPRs
typedef __attribute__((ext_vector_type(4))) float f32x4;

__device__ __forceinline__ short f2bf(float x) {
    unsigned u = __float_as_uint(x);
    unsigned r = (u + 0x7FFFu + ((u >> 16) & 1u)) >> 16;   // RNE
    return (short)r;
}

// ---------------------------------------------------------------------------
// prep: wT[n][k] = bf16(w[k][n]); zero row/col sums + d_out.
// ---------------------------------------------------------------------------
__global__ __launch_bounds__(256) void prep_kernel(
    const float* __restrict__ w, ushort* __restrict__ wT,
    float* __restrict__ sums, float* __restrict__ out, int out_size)
{
    int n = blockIdx.x, k = threadIdx.x;
    wT[(size_t)n * PDIM + k] = (ushort)f2bf(w[(size_t)k * PDIM + n]);
    int g = n * 256 + k;
    if (g < BDIM * UDIM + BDIM * EDIM) sums[g] = 0.f;
    if (g < out_size) out[g] = 0.f;
}

// ---------------------------------------------------------------------------
// proj: u_p/e_p = bf16(enc @ w + bias). MFMA 16x16x32, software-pipelined
// K-loop (prefetch next k-step's A fp32 + B bf16 frags during MFMA).
// ---------------------------------------------------------------------------
__global__ __launch_bounds__(256) void proj_kernel(
    const float* __restrict__ u_enc, const float* __restrict__ e_enc,
    const ushort* __restrict__ wT, const float* __restrict__ bias,
    ushort* __restrict__ u_p, ushort* __restrict__ e_p)
{
    int row0 = blockIdx.x * 64;
    int col0 = blockIdx.y * 64;
    const float* A; ushort* C;
    if (row0 < BDIM * UDIM) { A = u_enc; C = u_p; }
    else                    { A = e_enc; C = e_p; row0 -= BDIM * UDIM; }

    int tid  = threadIdx.x;
    int wave = tid >> 6, lane = tid & 63;
    int m = lane & 15, quad = lane >> 4;

    const float*  aptr = A + (size_t)(row0 + wave * 16 + m) * DDIM + quad * 8;
    const ushort* bptr = wT + (size_t)(col0 + m) * DDIM + quad * 8;

    f32x4 acc[4] = {};

    float4 a0c = *(const float4*)(aptr);
    float4 a1c = *(const float4*)(aptr + 4);
    bf16x8 bc[4];
    #pragma unroll
    for (int nt = 0; nt < 4; ++nt)
        bc[nt] = *(const bf16x8*)(bptr + (size_t)nt * 16 * DDIM);

    #pragma unroll
    for (int k0 = 32; k0 <= DDIM; k0 += 32) {
        float4 a0n, a1n; bf16x8 bn[4];
        if (k0 < DDIM) {
            a0n = *(const float4*)(aptr + k0);
            a1n = *(const float4*)(aptr + k0 + 4);
            #pragma unroll
            for (int nt = 0; nt < 4; ++nt)
                bn[nt] = *(const bf16x8*)(bptr + (size_t)nt * 16 * DDIM + k0);
        }
        bf16x8 af;
        af[0] = f2bf(a0c.x); af[1] = f2bf(a0c.y); af[2] = f2bf(a0c.z); af[3] = f2bf(a0c.w);
        af[4] = f2bf(a1c.x); af[5] = f2bf(a1c.y); af[6] = f2bf(a1c.z); af[7] = f2bf(a1c.w);
        #pragma unroll
        for (int nt = 0; nt < 4; ++nt)
            acc[nt] = __builtin_amdgcn_mfma_f32_16x16x32_bf16(af, bc[nt], acc[nt], 0, 0, 0);
        if (k0 < DDIM) {
            a0c = a0n; a1c = a1n;
            #pragma unroll
            for (int nt = 0; nt < 4; ++nt) bc[nt] = bn[nt];
        }
    }

    // C/D layout: col = lane&15, row = quad*4 + reg.
    #pragma unroll
    for (int nt = 0; nt < 4; ++nt) {
        int col = col0 + nt * 16 + m;
        float bv = bias[col];
        #pragma unroll
        for (int r = 0; r < 4; ++r) {
            int row = row0 + wave * 16 + quad * 4 + r;
            C[(size_t)row * PDIM + col] = (ushort)f2bf(acc[nt][r] + bv);
        }
    }
}

// ---------------------------------------------------------------------------
// fused: op = u_p . e_p (MFMA, pipelined), gate, row/col reduction.
// Epilogue: load-all-then-compute (32 nontemporal loads in flight).
// ---------------------------------------------------------------------------
__global__ __launch_bounds__(256) void fused_kernel(
    const ushort* __restrict__ u_p, const ushort* __restrict__ e_p,
    const float* __restrict__ pair_enc, const float* __restrict__ ue_mask,
    const float* __restrict__ bpp_w_p, const float* __restrict__ bpp_b_p,
    float* __restrict__ row_sums, float* __restrict__ col_sums)
{
    __shared__ float colred[4][64];

    int b  = blockIdx.y;
    int iu = blockIdx.x >> 4, ie = blockIdx.x & 15;
    int u0 = iu * 64, e0 = ie * 64;

    int tid  = threadIdx.x;
    int wave = tid >> 6, lane = tid & 63;
    int m = lane & 15, quad = lane >> 4;

    const ushort* Au = u_p + (size_t)b * UDIM * PDIM + (size_t)(u0 + wave * 16 + m) * PDIM + quad * 8;
    const ushort* Be = e_p + (size_t)b * EDIM * PDIM + (size_t)(e0 + m) * PDIM + quad * 8;

    f32x4 acc[4] = {};

    bf16x8 ac = *(const bf16x8*)(Au);
    bf16x8 bc[4];
    #pragma unroll
    for (int nt = 0; nt < 4; ++nt)
        bc[nt] = *(const bf16x8*)(Be + (size_t)nt * 16 * PDIM);

    #pragma unroll
    for (int k0 = 32; k0 <= PDIM; k0 += 32) {
        bf16x8 an, bn[4];
        if (k0 < PDIM) {
            an = *(const bf16x8*)(Au + k0);
            #pragma unroll
            for (int nt = 0; nt < 4; ++nt)
                bn[nt] = *(const bf16x8*)(Be + (size_t)nt * 16 * PDIM + k0);
        }
        #pragma unroll
        for (int nt = 0; nt < 4; ++nt)
            acc[nt] = __builtin_amdgcn_mfma_f32_16x16x32_bf16(ac, bc[nt], acc[nt], 0, 0, 0);
        if (k0 < PDIM) {
            ac = an;
            #pragma unroll
            for (int nt = 0; nt < 4; ++nt) bc[nt] = bn[nt];
        }
    }

    // Epilogue phase 1: batch-issue all pair/mask loads (nontemporal — no reuse).
    float bw = bpp_w_p[0], bb = bpp_b_p[0];
    const float* pm = pair_enc + (size_t)b * UDIM * EDIM;
    const float* mm = ue_mask  + (size_t)b * UDIM * EDIM;

    float mv[16], pv[16];
    #pragma unroll
    for (int r = 0; r < 4; ++r) {
        int row = u0 + wave * 16 + quad * 4 + r;
        #pragma unroll
        for (int nt = 0; nt < 4; ++nt) {
            size_t idx = (size_t)row * EDIM + (e0 + nt * 16 + m);
            mv[r * 4 + nt] = __builtin_nontemporal_load(&mm[idx]);
            pv[r * 4 + nt] = __builtin_nontemporal_load(&pm[idx]);
        }
    }

    // Epilogue phase 2: gate + partial sums. C layout: row=quad*4+r, col=nt*16+m.
    float rsum[4] = {0.f, 0.f, 0.f, 0.f};
    float csum[4] = {0.f, 0.f, 0.f, 0.f};
    #pragma unroll
    for (int r = 0; r < 4; ++r) {
        #pragma unroll
        for (int nt = 0; nt < 4; ++nt) {
            float mvv = mv[r * 4 + nt], pvv = pv[r * 4 + nt];
            float arg = bw * pvv + bb + mvv * acc[nt][r];
            float s = mvv / (1.f + __expf(-arg));
            rsum[r]  += s;
            csum[nt] += s;
        }
    }

    // Row sums: reduce across the 16 lanes of each quad; quad leader atomics.
    #pragma unroll
    for (int r = 0; r < 4; ++r) {
        float v = rsum[r];
        v += __shfl_xor(v, 1); v += __shfl_xor(v, 2);
        v += __shfl_xor(v, 4); v += __shfl_xor(v, 8);
        if (m == 0)
            atomicAdd(&row_sums[(size_t)b * UDIM + u0 + wave * 16 + quad * 4 + r], v);
    }

    // Col sums: reduce across quads, then across waves via LDS.
    #pragma unroll
    for (int nt = 0; nt < 4; ++nt) {
        float v = csum[nt];
        v += __shfl_xor(v, 16); v += __shfl_xor(v, 32);
        if (quad == 0) colred[wave][nt * 16 + m] = v;
    }
    __syncthreads();

    if (tid < 64) {
        float v = colred[0][tid] + colred[1][tid] + colred[2][tid] + colred[3][tid];
        atomicAdd(&col_sums[(size_t)b * EDIM + e0 + tid], v);
    }
}

// ---------------------------------------------------------------------------
// finish: out[b,0:256] = row_sums[b,:]@u_enc[b]; out[b,256:512] = col_sums@e_enc.
// grid (B,2,64): 16 rows/block, 4 independent accumulators -> high MLP.
// ---------------------------------------------------------------------------
__global__ __launch_bounds__(256) void finish_kernel(
    const float* __restrict__ u_enc, const float* __restrict__ e_enc,
    const float* __restrict__ row_sums, const float* __restrict__ col_sums,
    float* __restrict__ out)
{
    int b = blockIdx.x;
    int half = blockIdx.y;
    int chunk = blockIdx.z;          // 64 chunks of 16 rows
    int d = threadIdx.x;

    const float* enc = half ? e_enc : u_enc;
    const float* s   = half ? col_sums : row_sums;

    int base = chunk * 16;
    float sv[16];
    #pragma unroll
    for (int u = 0; u < 16; ++u) sv[u] = s[(size_t)b * UDIM + base + u];

    float a0 = 0.f, a1 = 0.f, a2 = 0.f, a3 = 0.f;
    #pragma unroll
    for (int u = 0; u < 16; u += 4) {
        a0 += sv[u + 0] * enc[(size_t)(b * UDIM + base + u + 0) * DDIM + d];
        a1 += sv[u + 1] * enc[(size_t)(b * UDIM + base + u + 1) * DDIM + d];
        a2 += sv[u + 2] * enc[(size_t)(b * UDIM + base + u + 2) * DDIM + d];
        a3 += sv[u + 3] * enc[(size_t)(b * UDIM + base + u + 3) * DDIM + d];
    }
    atomicAdd(&out[(size_t)b * 2 * DDIM + half * DDIM + d], (a0 + a1) + (a2 + a3));
}

// ---------------------------------------------------------------------------
extern "C" void kernel_launch(void* const* d_in, const int* in_sizes, int n_in,
                              void* d_out, int out_size, void* d_ws, size_t ws_size,
                              hipStream_t stream)
{
    const float* u_enc    = (const float*)d_in[0];
    const float* e_enc    = (const float*)d_in[1];
    const float* pair_enc = (const float*)d_in[2];
    const float* ue_mask  = (const float*)d_in[3];
    const float* w_kernel = (const float*)d_in[4];
    const float* w_bias   = (const float*)d_in[5];
    const float* bpp_w    = (const float*)d_in[6];
    const float* bpp_b    = (const float*)d_in[7];
    float* out = (float*)d_out;

    // ws layout: u_p bf16 (4MB) | e_p bf16 (4MB) | wT bf16 (128KB) | sums fp32 (64KB)
    ushort* u_p = (ushort*)d_ws;
    ushort* e_p = u_p + (size_t)BDIM * UDIM * PDIM;
    ushort* wT  = e_p + (size_t)BDIM * EDIM * PDIM;
    float* row_sums = (float*)(wT + (size_t)DDIM * PDIM);
    float* col_sums = row_sums + BDIM * UDIM;

    prep_kernel<<<dim3(256), 256, 0, stream>>>(w_kernel, wT, row_sums, out, out_size);

    proj_kernel<<<dim3(256, 4), 256, 0, stream>>>(u_enc, e_enc, wT, w_bias, u_p, e_p);

    fused_kernel<<<dim3(256, BDIM), 256, 0, stream>>>(u_p, e_p, pair_enc, ue_mask,
                                                      bpp_w, bpp_b, row_sums, col_sums);

    finish_kernel<<<dim3(BDIM, 2, 64), 256, 0, stream>>>(u_enc, e_enc, row_sums, col_sums, out);
}

// Round 4
// 188.464 us; speedup vs baseline: 1.0009x; 1.0009x over previous
//
#include <hip/hip_runtime.h>

// Problem constants (SubOut_60206851555968): B=8, U=E=1024, D=P=256, fp32 in/out.
#define BDIM 8
#define UDIM 1024
#define EDIM 1024
#define DDIM 256
#define PDIM 256

typedef __attribute__((ext_vector_type(8))) short bf16x8;   // 8 bf16 = 4 VGPRs
typedef __attribute__((ext_vector_type(4))) float f32x4;

__device__ __forceinline__ short f2bf(float x) {
    unsigned u = __float_as_uint(x);
    unsigned r = (u + 0x7FFFu + ((u >> 16) & 1u)) >> 16;   // RNE
    return (short)r;
}

// ---------------------------------------------------------------------------
// prep: wT[n][k] = bf16(w[k][n]); zero row/col sums + d_out.
// ---------------------------------------------------------------------------
__global__ __launch_bounds__(256) void prep_kernel(
    const float* __restrict__ w, ushort* __restrict__ wT,
    float* __restrict__ sums, float* __restrict__ out, int out_size)
{
    int n = blockIdx.x, k = threadIdx.x;
    wT[(size_t)n * PDIM + k] = (ushort)f2bf(w[(size_t)k * PDIM + n]);
    int g = n * 256 + k;
    if (g < BDIM * UDIM + BDIM * EDIM) sums[g] = 0.f;
    if (g < out_size) out[g] = 0.f;
}

// ---------------------------------------------------------------------------
// proj: u_p/e_p = bf16(enc @ w + bias). MFMA 16x16x32.
// All 16 A-row float4 loads (the HBM stream) are issued upfront and pinned
// with sched_barrier(0); B frags (wT, 128 KB, L1/L2-resident) load in-loop.
// ---------------------------------------------------------------------------
__global__ __launch_bounds__(256) void proj_kernel(
    const float* __restrict__ u_enc, const float* __restrict__ e_enc,
    const ushort* __restrict__ wT, const float* __restrict__ bias,
    ushort* __restrict__ u_p, ushort* __restrict__ e_p)
{
    int row0 = blockIdx.x * 64;
    int col0 = blockIdx.y * 64;
    const float* A; ushort* C;
    if (row0 < BDIM * UDIM) { A = u_enc; C = u_p; }
    else                    { A = e_enc; C = e_p; row0 -= BDIM * UDIM; }

    int tid  = threadIdx.x;
    int wave = tid >> 6, lane = tid & 63;
    int m = lane & 15, quad = lane >> 4;

    const float*  aptr = A + (size_t)(row0 + wave * 16 + m) * DDIM + quad * 8;
    const ushort* bptr = wT + (size_t)(col0 + m) * DDIM + quad * 8;

    // Batch-issue the entire A row (64 floats/lane = 16 float4 loads, all HBM).
    float4 a[16];
    #pragma unroll
    for (int s = 0; s < 8; ++s) {
        a[2 * s]     = *(const float4*)(aptr + s * 32);
        a[2 * s + 1] = *(const float4*)(aptr + s * 32 + 4);
    }
    __builtin_amdgcn_sched_barrier(0);   // do not sink these loads

    f32x4 acc[4] = {};

    #pragma unroll
    for (int s = 0; s < 8; ++s) {
        float4 a0 = a[2 * s], a1 = a[2 * s + 1];
        bf16x8 af;
        af[0] = f2bf(a0.x); af[1] = f2bf(a0.y); af[2] = f2bf(a0.z); af[3] = f2bf(a0.w);
        af[4] = f2bf(a1.x); af[5] = f2bf(a1.y); af[6] = f2bf(a1.z); af[7] = f2bf(a1.w);
        #pragma unroll
        for (int nt = 0; nt < 4; ++nt) {
            bf16x8 bfr = *(const bf16x8*)(bptr + (size_t)nt * 16 * DDIM + s * 32);
            acc[nt] = __builtin_amdgcn_mfma_f32_16x16x32_bf16(af, bfr, acc[nt], 0, 0, 0);
        }
    }

    // C/D layout: col = lane&15, row = quad*4 + reg.
    #pragma unroll
    for (int nt = 0; nt < 4; ++nt) {
        int col = col0 + nt * 16 + m;
        float bv = bias[col];
        #pragma unroll
        for (int r = 0; r < 4; ++r) {
            int row = row0 + wave * 16 + quad * 4 + r;
            C[(size_t)row * PDIM + col] = (ushort)f2bf(acc[nt][r] + bv);
        }
    }
}

// ---------------------------------------------------------------------------
// fused: op = u_p . e_p (MFMA), gate, row/col reduction.
// The 64 MB pair/mask HBM stream is batch-issued BEFORE the K-loop and pinned
// with sched_barrier(0) so it stays in flight under the whole MFMA chain.
// ---------------------------------------------------------------------------
__global__ __launch_bounds__(256) void fused_kernel(
    const ushort* __restrict__ u_p, const ushort* __restrict__ e_p,
    const float* __restrict__ pair_enc, const float* __restrict__ ue_mask,
    const float* __restrict__ bpp_w_p, const float* __restrict__ bpp_b_p,
    float* __restrict__ row_sums, float* __restrict__ col_sums)
{
    __shared__ float colred[4][64];

    int b  = blockIdx.y;
    int iu = blockIdx.x >> 4, ie = blockIdx.x & 15;
    int u0 = iu * 64, e0 = ie * 64;

    int tid  = threadIdx.x;
    int wave = tid >> 6, lane = tid & 63;
    int m = lane & 15, quad = lane >> 4;

    const float* pm = pair_enc + (size_t)b * UDIM * EDIM;
    const float* mm = ue_mask  + (size_t)b * UDIM * EDIM;

    // Phase 0: batch-issue all 32 pair/mask loads (nontemporal, zero reuse).
    float mv[16], pv[16];
    #pragma unroll
    for (int r = 0; r < 4; ++r) {
        int row = u0 + wave * 16 + quad * 4 + r;
        #pragma unroll
        for (int nt = 0; nt < 4; ++nt) {
            size_t idx = (size_t)row * EDIM + (e0 + nt * 16 + m);
            mv[r * 4 + nt] = __builtin_nontemporal_load(&mm[idx]);
            pv[r * 4 + nt] = __builtin_nontemporal_load(&pm[idx]);
        }
    }
    __builtin_amdgcn_sched_barrier(0);   // pin the HBM batch ahead of the K-loop

    const ushort* Au = u_p + (size_t)b * UDIM * PDIM + (size_t)(u0 + wave * 16 + m) * PDIM + quad * 8;
    const ushort* Be = e_p + (size_t)b * EDIM * PDIM + (size_t)(e0 + m) * PDIM + quad * 8;

    f32x4 acc[4] = {};

    #pragma unroll
    for (int k0 = 0; k0 < PDIM; k0 += 32) {
        bf16x8 af = *(const bf16x8*)(Au + k0);
        #pragma unroll
        for (int nt = 0; nt < 4; ++nt) {
            bf16x8 bfr = *(const bf16x8*)(Be + (size_t)nt * 16 * PDIM + k0);
            acc[nt] = __builtin_amdgcn_mfma_f32_16x16x32_bf16(af, bfr, acc[nt], 0, 0, 0);
        }
    }

    // Epilogue: gate + partial sums. C layout: row=quad*4+r, col=nt*16+m.
    float bw = bpp_w_p[0], bb = bpp_b_p[0];
    float rsum[4] = {0.f, 0.f, 0.f, 0.f};
    float csum[4] = {0.f, 0.f, 0.f, 0.f};
    #pragma unroll
    for (int r = 0; r < 4; ++r) {
        #pragma unroll
        for (int nt = 0; nt < 4; ++nt) {
            float mvv = mv[r * 4 + nt], pvv = pv[r * 4 + nt];
            float arg = bw * pvv + bb + mvv * acc[nt][r];
            float s = mvv / (1.f + __expf(-arg));
            rsum[r]  += s;
            csum[nt] += s;
        }
    }

    // Row sums: reduce across the 16 lanes of each quad; quad leader atomics.
    #pragma unroll
    for (int r = 0; r < 4; ++r) {
        float v = rsum[r];
        v += __shfl_xor(v, 1); v += __shfl_xor(v, 2);
        v += __shfl_xor(v, 4); v += __shfl_xor(v, 8);
        if (m == 0)
            atomicAdd(&row_sums[(size_t)b * UDIM + u0 + wave * 16 + quad * 4 + r], v);
    }

    // Col sums: reduce across quads, then across waves via LDS.
    #pragma unroll
    for (int nt = 0; nt < 4; ++nt) {
        float v = csum[nt];
        v += __shfl_xor(v, 16); v += __shfl_xor(v, 32);
        if (quad == 0) colred[wave][nt * 16 + m] = v;
    }
    __syncthreads();

    if (tid < 64) {
        float v = colred[0][tid] + colred[1][tid] + colred[2][tid] + colred[3][tid];
        atomicAdd(&col_sums[(size_t)b * EDIM + e0 + tid], v);
    }
}

// ---------------------------------------------------------------------------
// finish: out[b,0:256] = row_sums[b,:]@u_enc[b]; out[b,256:512] = col_sums@e_enc.
// grid (B,2,64): 16 rows/block, 4 independent accumulator chains.
// ---------------------------------------------------------------------------
__global__ __launch_bounds__(256) void finish_kernel(
    const float* __restrict__ u_enc, const float* __restrict__ e_enc,
    const float* __restrict__ row_sums, const float* __restrict__ col_sums,
    float* __restrict__ out)
{
    int b = blockIdx.x;
    int half = blockIdx.y;
    int chunk = blockIdx.z;          // 64 chunks of 16 rows
    int d = threadIdx.x;

    const float* enc = half ? e_enc : u_enc;
    const float* s   = half ? col_sums : row_sums;

    int base = chunk * 16;
    float sv[16];
    #pragma unroll
    for (int u = 0; u < 16; ++u) sv[u] = s[(size_t)b * UDIM + base + u];

    float a0 = 0.f, a1 = 0.f, a2 = 0.f, a3 = 0.f;
    #pragma unroll
    for (int u = 0; u < 16; u += 4) {
        a0 += sv[u + 0] * enc[(size_t)(b * UDIM + base + u + 0) * DDIM + d];
        a1 += sv[u + 1] * enc[(size_t)(b * UDIM + base + u + 1) * DDIM + d];
        a2 += sv[u + 2] * enc[(size_t)(b * UDIM + base + u + 2) * DDIM + d];
        a3 += sv[u + 3] * enc[(size_t)(b * UDIM + base + u + 3) * DDIM + d];
    }
    atomicAdd(&out[(size_t)b * 2 * DDIM + half * DDIM + d], (a0 + a1) + (a2 + a3));
}

// ---------------------------------------------------------------------------
extern "C" void kernel_launch(void* const* d_in, const int* in_sizes, int n_in,
                              void* d_out, int out_size, void* d_ws, size_t ws_size,
                              hipStream_t stream)
{
    const float* u_enc    = (const float*)d_in[0];
    const float* e_enc    = (const float*)d_in[1];
    const float* pair_enc = (const float*)d_in[2];
    const float* ue_mask  = (const float*)d_in[3];
    const float* w_kernel = (const float*)d_in[4];
    const float* w_bias   = (const float*)d_in[5];
    const float* bpp_w    = (const float*)d_in[6];
    const float* bpp_b    = (const float*)d_in[7];
    float* out = (float*)d_out;

    // ws layout: u_p bf16 (4MB) | e_p bf16 (4MB) | wT bf16 (128KB) | sums fp32 (64KB)
    ushort* u_p = (ushort*)d_ws;
    ushort* e_p = u_p + (size_t)BDIM * UDIM * PDIM;
    ushort* wT  = e_p + (size_t)BDIM * EDIM * PDIM;
    float* row_sums = (float*)(wT + (size_t)DDIM * PDIM);
    float* col_sums = row_sums + BDIM * UDIM;

    prep_kernel<<<dim3(256), 256, 0, stream>>>(w_kernel, wT, row_sums, out, out_size);

    proj_kernel<<<dim3(256, 4), 256, 0, stream>>>(u_enc, e_enc, wT, w_bias, u_p, e_p);

    fused_kernel<<<dim3(256, BDIM), 256, 0, stream>>>(u_p, e_p, pair_enc, ue_mask,
                                                      bpp_w, bpp_b, row_sums, col_sums);

    finish_kernel<<<dim3(BDIM, 2, 64), 256, 0, stream>>>(u_enc, e_enc, row_sums, col_sums, out);
}

// Round 5
// 182.006 us; speedup vs baseline: 1.0364x; 1.0355x over previous
//
#include <hip/hip_runtime.h>

// Problem constants (SubOut_60206851555968): B=8, U=E=1024, D=P=256, fp32 in/out.
#define BDIM 8
#define UDIM 1024
#define EDIM 1024
#define DDIM 256
#define PDIM 256

typedef __attribute__((ext_vector_type(8))) short bf16x8;   // 8 bf16 = 4 VGPRs
typedef __attribute__((ext_vector_type(4))) float f32x4;
typedef __attribute__((ext_vector_type(4))) unsigned short u16x4;

__device__ __forceinline__ short f2bf(float x) {
    unsigned u = __float_as_uint(x);
    unsigned r = (u + 0x7FFFu + ((u >> 16) & 1u)) >> 16;   // RNE
    return (short)r;
}

// ---------------------------------------------------------------------------
// prep: wT[n][k] = bf16(w[k][n]); zero row/col sums + d_out.
// ---------------------------------------------------------------------------
__global__ __launch_bounds__(256) void prep_kernel(
    const float* __restrict__ w, ushort* __restrict__ wT,
    float* __restrict__ sums, float* __restrict__ out, int out_size)
{
    int n = blockIdx.x, k = threadIdx.x;
    wT[(size_t)n * PDIM + k] = (ushort)f2bf(w[(size_t)k * PDIM + n]);
    int g = n * 256 + k;
    if (g < BDIM * UDIM + BDIM * EDIM) sums[g] = 0.f;
    if (g < out_size) out[g] = 0.f;
}

// ---------------------------------------------------------------------------
// proj: u_p/e_p = bf16(enc @ w + bias). MFMA 16x16x32.
// Column permutation: B-tile nt is loaded from physical col m*4+nt, so lane m
// owns 4 consecutive output cols -> vectorized ushort4 stores.
// ---------------------------------------------------------------------------
__global__ __launch_bounds__(256) void proj_kernel(
    const float* __restrict__ u_enc, const float* __restrict__ e_enc,
    const ushort* __restrict__ wT, const float* __restrict__ bias,
    ushort* __restrict__ u_p, ushort* __restrict__ e_p)
{
    int row0 = blockIdx.x * 64;
    int col0 = blockIdx.y * 64;
    const float* A; ushort* C;
    if (row0 < BDIM * UDIM) { A = u_enc; C = u_p; }
    else                    { A = e_enc; C = e_p; row0 -= BDIM * UDIM; }

    int tid  = threadIdx.x;
    int wave = tid >> 6, lane = tid & 63;
    int m = lane & 15, quad = lane >> 4;

    const float*  aptr = A + (size_t)(row0 + wave * 16 + m) * DDIM + quad * 8;
    const ushort* bptr = wT + (size_t)(col0 + m * 4) * DDIM + quad * 8;   // physical col m*4+nt

    // Batch-issue the entire A row (64 floats/lane = 16 float4 loads, all HBM).
    float4 a[16];
    #pragma unroll
    for (int s = 0; s < 8; ++s) {
        a[2 * s]     = *(const float4*)(aptr + s * 32);
        a[2 * s + 1] = *(const float4*)(aptr + s * 32 + 4);
    }
    __builtin_amdgcn_sched_barrier(0);   // do not sink these loads

    f32x4 acc[4] = {};

    #pragma unroll
    for (int s = 0; s < 8; ++s) {
        float4 a0 = a[2 * s], a1 = a[2 * s + 1];
        bf16x8 af;
        af[0] = f2bf(a0.x); af[1] = f2bf(a0.y); af[2] = f2bf(a0.z); af[3] = f2bf(a0.w);
        af[4] = f2bf(a1.x); af[5] = f2bf(a1.y); af[6] = f2bf(a1.z); af[7] = f2bf(a1.w);
        #pragma unroll
        for (int nt = 0; nt < 4; ++nt) {
            bf16x8 bfr = *(const bf16x8*)(bptr + (size_t)nt * DDIM + s * 32);
            acc[nt] = __builtin_amdgcn_mfma_f32_16x16x32_bf16(af, bfr, acc[nt], 0, 0, 0);
        }
    }

    // acc[nt][r]: row = wave*16 + quad*4 + r, col = col0 + m*4 + nt.
    float4 bv = *(const float4*)&bias[col0 + m * 4];
    #pragma unroll
    for (int r = 0; r < 4; ++r) {
        int row = row0 + wave * 16 + quad * 4 + r;
        u16x4 o;
        o[0] = (ushort)f2bf(acc[0][r] + bv.x);
        o[1] = (ushort)f2bf(acc[1][r] + bv.y);
        o[2] = (ushort)f2bf(acc[2][r] + bv.z);
        o[3] = (ushort)f2bf(acc[3][r] + bv.w);
        *(u16x4*)&C[(size_t)row * PDIM + col0 + m * 4] = o;
    }
}

// ---------------------------------------------------------------------------
// fused: op = u_p . e_p (MFMA), gate, row/col reduction.
// Same column permutation -> pair/mask are float4 (16 B/lane) coalesced loads,
// batch-issued before the K-loop and pinned so the HBM stream stays in flight.
// ---------------------------------------------------------------------------
__global__ __launch_bounds__(256) void fused_kernel(
    const ushort* __restrict__ u_p, const ushort* __restrict__ e_p,
    const float* __restrict__ pair_enc, const float* __restrict__ ue_mask,
    const float* __restrict__ bpp_w_p, const float* __restrict__ bpp_b_p,
    float* __restrict__ row_sums, float* __restrict__ col_sums)
{
    __shared__ float colred[4][64];

    int b  = blockIdx.y;
    int iu = blockIdx.x >> 4, ie = blockIdx.x & 15;
    int u0 = iu * 64, e0 = ie * 64;

    int tid  = threadIdx.x;
    int wave = tid >> 6, lane = tid & 63;
    int m = lane & 15, quad = lane >> 4;

    const float* pm = pair_enc + (size_t)b * UDIM * EDIM;
    const float* mm = ue_mask  + (size_t)b * UDIM * EDIM;

    // Phase 0: batch-issue all pair/mask loads as float4 (col = e0 + 4m .. +3).
    float4 mv[4], pv[4];
    #pragma unroll
    for (int r = 0; r < 4; ++r) {
        size_t idx = (size_t)(u0 + wave * 16 + quad * 4 + r) * EDIM + e0 + m * 4;
        mv[r] = *(const float4*)&mm[idx];
        pv[r] = *(const float4*)&pm[idx];
    }
    __builtin_amdgcn_sched_barrier(0);   // pin the HBM batch ahead of the K-loop

    const ushort* Au = u_p + (size_t)b * UDIM * PDIM + (size_t)(u0 + wave * 16 + m) * PDIM + quad * 8;
    const ushort* Be = e_p + (size_t)b * EDIM * PDIM + (size_t)(e0 + m * 4) * PDIM + quad * 8;

    f32x4 acc[4] = {};

    #pragma unroll
    for (int k0 = 0; k0 < PDIM; k0 += 32) {
        bf16x8 af = *(const bf16x8*)(Au + k0);
        #pragma unroll
        for (int nt = 0; nt < 4; ++nt) {
            bf16x8 bfr = *(const bf16x8*)(Be + (size_t)nt * PDIM + k0);   // physical col m*4+nt
            acc[nt] = __builtin_amdgcn_mfma_f32_16x16x32_bf16(af, bfr, acc[nt], 0, 0, 0);
        }
    }

    // Epilogue: lane (quad,m), reg r -> row = u0+wave*16+quad*4+r, col = e0+m*4+nt.
    float bw = bpp_w_p[0], bb = bpp_b_p[0];
    float rsum[4];
    float csum[4] = {0.f, 0.f, 0.f, 0.f};
    #pragma unroll
    for (int r = 0; r < 4; ++r) {
        float mvv[4] = {mv[r].x, mv[r].y, mv[r].z, mv[r].w};
        float pvv[4] = {pv[r].x, pv[r].y, pv[r].z, pv[r].w};
        float rs = 0.f;
        #pragma unroll
        for (int nt = 0; nt < 4; ++nt) {
            float arg = bw * pvv[nt] + bb + mvv[nt] * acc[nt][r];
            float s = mvv[nt] / (1.f + __expf(-arg));
            rs       += s;
            csum[nt] += s;
        }
        rsum[r] = rs;
    }

    // Row sums: reduce across the 16 m-lanes of each quad; quad leader atomics.
    #pragma unroll
    for (int r = 0; r < 4; ++r) {
        float v = rsum[r];
        v += __shfl_xor(v, 1); v += __shfl_xor(v, 2);
        v += __shfl_xor(v, 4); v += __shfl_xor(v, 8);
        if (m == 0)
            atomicAdd(&row_sums[(size_t)b * UDIM + u0 + wave * 16 + quad * 4 + r], v);
    }

    // Col sums: reduce across quads (rows), then across waves via LDS.
    #pragma unroll
    for (int nt = 0; nt < 4; ++nt) {
        float v = csum[nt];
        v += __shfl_xor(v, 16); v += __shfl_xor(v, 32);
        if (quad == 0) colred[wave][m * 4 + nt] = v;   // col - e0 = m*4 + nt
    }
    __syncthreads();

    if (tid < 64) {
        float v = colred[0][tid] + colred[1][tid] + colred[2][tid] + colred[3][tid];
        atomicAdd(&col_sums[(size_t)b * EDIM + e0 + tid], v);
    }
}

// ---------------------------------------------------------------------------
// finish: out[b,0:256] = row_sums[b,:]@u_enc[b]; out[b,256:512] = col_sums@e_enc.
// grid (B,2,64): 16 rows/block, 4 independent accumulator chains.
// ---------------------------------------------------------------------------
__global__ __launch_bounds__(256) void finish_kernel(
    const float* __restrict__ u_enc, const float* __restrict__ e_enc,
    const float* __restrict__ row_sums, const float* __restrict__ col_sums,
    float* __restrict__ out)
{
    int b = blockIdx.x;
    int half = blockIdx.y;
    int chunk = blockIdx.z;          // 64 chunks of 16 rows
    int d = threadIdx.x;

    const float* enc = half ? e_enc : u_enc;
    const float* s   = half ? col_sums : row_sums;

    int base = chunk * 16;
    float sv[16];
    #pragma unroll
    for (int u = 0; u < 16; ++u) sv[u] = s[(size_t)b * UDIM + base + u];

    float a0 = 0.f, a1 = 0.f, a2 = 0.f, a3 = 0.f;
    #pragma unroll
    for (int u = 0; u < 16; u += 4) {
        a0 += sv[u + 0] * enc[(size_t)(b * UDIM + base + u + 0) * DDIM + d];
        a1 += sv[u + 1] * enc[(size_t)(b * UDIM + base + u + 1) * DDIM + d];
        a2 += sv[u + 2] * enc[(size_t)(b * UDIM + base + u + 2) * DDIM + d];
        a3 += sv[u + 3] * enc[(size_t)(b * UDIM + base + u + 3) * DDIM + d];
    }
    atomicAdd(&out[(size_t)b * 2 * DDIM + half * DDIM + d], (a0 + a1) + (a2 + a3));
}

// ---------------------------------------------------------------------------
extern "C" void kernel_launch(void* const* d_in, const int* in_sizes, int n_in,
                              void* d_out, int out_size, void* d_ws, size_t ws_size,
                              hipStream_t stream)
{
    const float* u_enc    = (const float*)d_in[0];
    const float* e_enc    = (const float*)d_in[1];
    const float* pair_enc = (const float*)d_in[2];
    const float* ue_mask  = (const float*)d_in[3];
    const float* w_kernel = (const float*)d_in[4];
    const float* w_bias   = (const float*)d_in[5];
    const float* bpp_w    = (const float*)d_in[6];
    const float* bpp_b    = (const float*)d_in[7];
    float* out = (float*)d_out;

    // ws layout: u_p bf16 (4MB) | e_p bf16 (4MB) | wT bf16 (128KB) | sums fp32 (64KB)
    ushort* u_p = (ushort*)d_ws;
    ushort* e_p = u_p + (size_t)BDIM * UDIM * PDIM;
    ushort* wT  = e_p + (size_t)BDIM * EDIM * PDIM;
    float* row_sums = (float*)(wT + (size_t)DDIM * PDIM);
    float* col_sums = row_sums + BDIM * UDIM;

    prep_kernel<<<dim3(256), 256, 0, stream>>>(w_kernel, wT, row_sums, out, out_size);

    proj_kernel<<<dim3(256, 4), 256, 0, stream>>>(u_enc, e_enc, wT, w_bias, u_p, e_p);

    fused_kernel<<<dim3(256, BDIM), 256, 0, stream>>>(u_p, e_p, pair_enc, ue_mask,
                                                      bpp_w, bpp_b, row_sums, col_sums);

    finish_kernel<<<dim3(BDIM, 2, 64), 256, 0, stream>>>(u_enc, e_enc, row_sums, col_sums, out);
}